// Round 9
// baseline (828.018 us; speedup 1.0000x reference)
//
#include <hip/hip_runtime.h>

typedef short bf16x8 __attribute__((ext_vector_type(8)));
typedef short bf16x4 __attribute__((ext_vector_type(4)));
typedef float f32x4  __attribute__((ext_vector_type(4)));

#define AS1 __attribute__((address_space(1)))
#define AS3 __attribute__((address_space(3)))

__device__ __forceinline__ void gload16(const void* g, void* l) {
  __builtin_amdgcn_global_load_lds((const AS1 void*)g, (AS3 void*)l, 16, 0, 0);
}

__device__ __forceinline__ short f2bf(float f) {
  union { float fv; unsigned u; } v; v.fv = f;
  unsigned r = v.u + 0x7fffu + ((v.u >> 16) & 1u);
  return (short)(r >> 16);
}

// truncating f32->bf16 (P in (0,256]; numerator & denominator share P so bias cancels)
__device__ __forceinline__ short f2bf_t(float f) {
  return (short)(__float_as_uint(f) >> 16);
}

// ---------------- fused cast x (fp32->bf16, float4/thread) + weight prep ----------------
__global__ void cast_prep_kernel(const float* __restrict__ x, const float* __restrict__ left_w,
                                 const float* __restrict__ diag, const float* __restrict__ right_w,
                                 short* __restrict__ xb, short* __restrict__ LT, short* __restrict__ WT) {
  long idx = (long)blockIdx.x * 256 + threadIdx.x;
  const long N4 = 4194304L;              // x elements / 4
  const long LTN = 4L * 128 * 2048;
  const long WTN = 4L * 16 * 128 * 256;
  if (idx < N4) {
    float4 v = ((const float4*)x)[idx];
    short4 s;
    s.x = f2bf(v.x); s.y = f2bf(v.y); s.z = f2bf(v.z); s.w = f2bf(v.w);
    ((short4*)xb)[idx] = s;
  } else if (idx < N4 + LTN) {
    long j = idx - N4;
    LT[j] = f2bf(left_w[j]);
  } else if (idx < N4 + LTN + WTN) {
    long j = idx - N4 - LTN;
    int d = (int)(j & 255);
    long rest = j >> 8;
    int e = (int)(rest & 127);
    long gi = rest >> 7;
    int i = (int)(gi >> 4), n = (int)(gi & 15);
    float v;
    if (d < 128) v = diag[(gi * 128 + d) * 128 + e];
    else         v = right_w[((long)i * 2048 + n * 128 + e) * 128 + (d - 128)];
    WT[j] = f2bf(v);
  }
}

// ---------------- 32x128-tile GEMM, double-buffered K (XOR-swizzled LDS): C = A @ BT^T ----------------
// Thin-N variant: M-tile 32, N-tile 128 -> grid (M/32, N/128). 4 waves, each 32(M)x32(N), acc[2][2].
__global__ __launch_bounds__(256) void gemm_bt(const short* __restrict__ A, const short* __restrict__ BT,
                                               short* __restrict__ C, int M, int N, int K) {
  __shared__ __align__(16) short As[2][32 * 64];    // 4KB per buf
  __shared__ __align__(16) short Bs[2][128 * 64];   // 16KB per buf
  int tid = threadIdx.x, w = tid >> 6, lane = tid & 63;
  int m0 = blockIdx.x * 32, n0 = blockIdx.y * 128;
  int wn = w * 32;
  int quad = lane >> 4, l16 = lane & 15;
  int srow = lane >> 3;
  int schunk = ((lane & 7) ^ srow) * 8;   // XOR-swizzled source chunk (matches read-side l16&7 XOR)

#define GSTAGE(K0, BUF) {                                                             \
    gload16(&A[(long)(m0 + w * 8 + srow) * K + (K0) + schunk], &As[BUF][(w * 8) * 64]); \
    for (int p = 0; p < 4; ++p) {                                                     \
      int r = p * 32 + w * 8 + srow;                                                  \
      gload16(&BT[(long)(n0 + r) * K + (K0) + schunk], &Bs[BUF][(p * 32 + w * 8) * 64]); \
    }                                                                                 \
  }

  f32x4 acc[2][2] = {};
  GSTAGE(0, 0)
  __syncthreads();
  int nk = K >> 6;
  for (int it = 0; it < nk; ++it) {
    int cur = it & 1;
    if (it + 1 < nk) GSTAGE((it + 1) * 64, cur ^ 1)   // prefetch overlaps compute
#pragma unroll
    for (int kk = 0; kk < 2; ++kk) {
      int c = (((kk * 4 + quad) ^ (l16 & 7)) * 8);
      bf16x8 a[2], b[2];
#pragma unroll
      for (int t = 0; t < 2; ++t) a[t] = *(const bf16x8*)&As[cur][(t * 16 + l16) * 64 + c];
#pragma unroll
      for (int t = 0; t < 2; ++t) b[t] = *(const bf16x8*)&Bs[cur][(wn + t * 16 + l16) * 64 + c];
#pragma unroll
      for (int mt = 0; mt < 2; ++mt)
#pragma unroll
        for (int nt = 0; nt < 2; ++nt)
          acc[mt][nt] = __builtin_amdgcn_mfma_f32_16x16x32_bf16(a[mt], b[nt], acc[mt][nt], 0, 0, 0);
    }
    __syncthreads();
  }
#undef GSTAGE
#pragma unroll
  for (int mt = 0; mt < 2; ++mt)
#pragma unroll
    for (int nt = 0; nt < 2; ++nt)
#pragma unroll
      for (int r = 0; r < 4; ++r) {
        int m = m0 + mt * 16 + quad * 4 + r;
        int n = n0 + wn + nt * 16 + l16;
        C[(long)m * N + n] = f2bf(acc[mt][nt][r]);
      }
}

// ---------------- grouped lori GEMM, double-buffered kt (XOR-swizzled LDS) ----------------
__global__ __launch_bounds__(256) void lori_gemm(const short* __restrict__ tok, const short* __restrict__ rnk,
                                                 int rstride, const short* __restrict__ WT,
                                                 const float* __restrict__ rb, const float* __restrict__ bp,
                                                 int i_base, short* __restrict__ qb, short* __restrict__ kb,
                                                 short* __restrict__ vT, float* __restrict__ out) {
  __shared__ __align__(16) short As[2][128 * 64];
  __shared__ __align__(16) short Bs[2][128 * 64];
  int tid = threadIdx.x, w = tid >> 6, lane = tid & 63;
  int i = i_base + (blockIdx.y >> 4);
  int n = blockIdx.y & 15;
  int t0 = blockIdx.x * 128;
  int co = (i < 3) ? i * 128 : 0;
  const short* WTn = WT + (long)(i * 16 + n) * 128 * 256;
  int wm = (w >> 1) * 64, wn = (w & 1) * 64;
  int quad = lane >> 4, l16 = lane & 15;
  int srow = lane >> 3;
  int schunk = ((lane & 7) ^ srow) * 8;

#define LSTAGE(KT, BUF) {                                                             \
    for (int p = 0; p < 4; ++p) {                                                     \
      int r = p * 32 + w * 8 + srow;                                                  \
      const short* ga;                                                                \
      if ((KT) < 2) ga = &tok[(long)(t0 + r) * 2048 + n * 128 + (KT) * 64 + schunk];  \
      else          ga = &rnk[(long)(t0 + r) * rstride + co + ((KT) - 2) * 64 + schunk]; \
      gload16(ga, &As[BUF][(p * 32 + w * 8) * 64]);                                   \
      gload16(&WTn[r * 256 + (KT) * 64 + schunk], &Bs[BUF][(p * 32 + w * 8) * 64]);   \
    }                                                                                 \
  }

  f32x4 acc[4][4] = {};
  LSTAGE(0, 0)
  __syncthreads();
#pragma unroll
  for (int kt = 0; kt < 4; ++kt) {
    int cur = kt & 1;
    if (kt < 3) LSTAGE(kt + 1, cur ^ 1)   // prefetch overlaps compute
#pragma unroll
    for (int kk = 0; kk < 2; ++kk) {
      int c = (((kk * 4 + quad) ^ (l16 & 7)) * 8);
      bf16x8 a[4], b[4];
#pragma unroll
      for (int t = 0; t < 4; ++t) a[t] = *(const bf16x8*)&As[cur][(wm + t * 16 + l16) * 64 + c];
#pragma unroll
      for (int t = 0; t < 4; ++t) b[t] = *(const bf16x8*)&Bs[cur][(wn + t * 16 + l16) * 64 + c];
#pragma unroll
      for (int mt = 0; mt < 4; ++mt)
#pragma unroll
        for (int nt = 0; nt < 4; ++nt)
          acc[mt][nt] = __builtin_amdgcn_mfma_f32_16x16x32_bf16(a[mt], b[nt], acc[mt][nt], 0, 0, 0);
    }
    __syncthreads();
  }
#undef LSTAGE
  int b = t0 >> 11;
  int tl0 = t0 & 2047;
  const float QSC = 0.08838834764831845f * 1.4426950408889634f;  // 1/sqrt(128) * log2(e)
#pragma unroll
  for (int mt = 0; mt < 4; ++mt) {
#pragma unroll
    for (int nt = 0; nt < 4; ++nt) {
      int e = wn + nt * 16 + l16;
      int c = n * 128 + e;
      float bias = rb[i * 2048 + c] + bp[i * 2048 + c];
      int tl = tl0 + wm + mt * 16 + quad * 4;
      if (i == 0) {
#pragma unroll
        for (int r = 0; r < 4; ++r)
          qb[((long)(b * 16 + n) * 2048 + tl + r) * 128 + e] = f2bf((acc[mt][nt][r] + bias) * QSC);
      } else if (i == 1) {
#pragma unroll
        for (int r = 0; r < 4; ++r)
          kb[((long)(b * 16 + n) * 2048 + tl + r) * 128 + e] = f2bf(acc[mt][nt][r] + bias);
      } else if (i == 2) {
        short4 s4;
        s4.x = f2bf(acc[mt][nt][0] + bias);
        s4.y = f2bf(acc[mt][nt][1] + bias);
        s4.z = f2bf(acc[mt][nt][2] + bias);
        s4.w = f2bf(acc[mt][nt][3] + bias);
        *(short4*)&vT[((long)(b * 16 + n) * 128 + e) * 2048 + tl] = s4;
      } else {
#pragma unroll
        for (int r = 0; r < 4; ++r)
          out[(long)(t0 + wm + mt * 16 + quad * 4 + r) * 2048 + c] = acc[mt][nt][r] + bias;
      }
    }
  }
}

// ---------------- flash attention v13: v12 minus V-LDS staging -> 16KB LDS, 8 blocks/CU ----------------
// (Round-8 submission never ran: container infra failure. Resubmitted unchanged for measurement.)
// vT[bh][d][t] is ALREADY in PV's consumption layout; the vs LDS buffer was a pure relay
// (its swizzled read de-swizzles to linear key nt*16+quad*4). Read V fragments (8B/lane)
// straight from global (L2/L3-resident, ~11 TB/s aggregate demand vs 34.5 TB/s L2 ceiling).
// LDS 32->16KB and launch_bounds(128,4): 8 blocks/CU (16 waves, 4/SIMD) vs v12's 5 blocks
// (~6 waves effective, Occupancy 19%). STAGE halves -> half the vmcnt drain per barrier.
// grid: 2048 = 64 bh x 32 q-tiles (64 rows each); long q-tiles dispatched first.
__global__ __launch_bounds__(128, 4) void attn_kernel(const short* __restrict__ qb, const short* __restrict__ kb,
                                                      const short* __restrict__ vT, short* __restrict__ y) {
  __shared__ __align__(16) short ks[64 * 128];   // K tile, 16-chunk XOR swizzle per row (16KB)
  int tid = threadIdx.x, w = tid >> 6, lane = tid & 63;
  int id = blockIdx.x;
  int bh = id & 63;                   // bh&7 = XCD pin for K/V L2 locality
  int qt = 31 - (id >> 6);            // q-tile (64 rows); long tiles first
  int b = bh >> 4, h = bh & 15;
  int quad = lane >> 4, l16 = lane & 15;

  // Q fragments global->VGPR; serve as B-operand (k=d=quad*8+j, n=q=l16) of S^T MFMA
  bf16x8 aq[2][4];
#pragma unroll
  for (int mt = 0; mt < 2; ++mt)
#pragma unroll
    for (int kk = 0; kk < 4; ++kk)
      aq[mt][kk] = *(const bf16x8*)&qb[((long)bh * 2048 + qt * 64 + w * 32 + mt * 16 + l16) * 128 + kk * 32 + quad * 8];

  f32x4 O[2][8] = {};                 // O^T tiles: row=d (quad*4+r within dt), col=q (l16)
  f32x4 Lacc[2] = {};                 // ones-MFMA row-sum accumulator (rows identical)
  float mst[2] = {-3.0e38f, -3.0e38f};
  const bf16x4 ones4 = {(short)0x3F80, (short)0x3F80, (short)0x3F80, (short)0x3F80};

  // staging lane constants (K only; V is read direct from global)
  int kq = lane >> 4;

  const short* kbase = kb + (long)bh * 2048 * 128;
  const short* vbase = vT + (long)bh * 128 * 2048;
  const short* vlane = vbase + (long)l16 * 2048 + quad * 4;   // + dt*16*2048 + jt*64 + nt*16 at use

  // stage split across 2 waves: wave w loads K rows w*32..w*32+31 (4 rows/instr, 8 instrs).
  // Swizzle identity preserved: (w*32+p*4+kq)&15 == (p*4+kq)&15.
#define STAGE(JT) {                                                                   \
    for (int p = 0; p < 8; ++p) {                                                     \
      int r = w * 32 + p * 4 + kq;                                                    \
      int kch = l16 ^ ((p * 4 + kq) & 15);                                            \
      gload16(&kbase[((long)((JT) * 64 + r)) * 128 + kch * 8], &ks[(w * 32 + p * 4) * 128]); \
    }                                                                                 \
  }

  for (int jt = 0; jt <= qt; ++jt) {
    if (jt) __syncthreads();          // both waves done reading previous tile
    STAGE(jt)
    __syncthreads();                  // stage landed (vmcnt drain folded in)

    // S^T = K·Q^T  (wave: 64 keys x 32 q)
    f32x4 s[2][4] = {};
#pragma unroll
    for (int nt = 0; nt < 4; ++nt)
#pragma unroll
      for (int kk = 0; kk < 4; ++kk) {
        bf16x8 bk = *(const bf16x8*)&ks[(nt * 16 + l16) * 128 + (((kk * 4 + quad) ^ l16) * 8)];
        s[0][nt] = __builtin_amdgcn_mfma_f32_16x16x32_bf16(bk, aq[0][kk], s[0][nt], 0, 0, 0);
        s[1][nt] = __builtin_amdgcn_mfma_f32_16x16x32_bf16(bk, aq[1][kk], s[1][nt], 0, 0, 0);
      }
    if (jt == qt) {   // diagonal tile: causal mask
#pragma unroll
      for (int mt = 0; mt < 2; ++mt)
#pragma unroll
        for (int nt = 0; nt < 4; ++nt) {
          int q = qt * 64 + w * 32 + mt * 16 + l16;
#pragma unroll
          for (int r = 0; r < 4; ++r) {
            int key = jt * 64 + nt * 16 + quad * 4 + r;
            if (key > q) s[mt][nt][r] = -3.0e38f;
          }
        }
    }
    bf16x4 pb[2][4];
#pragma unroll
    for (int mt = 0; mt < 2; ++mt) {
      // per-q max: in-register tree + 2 cross-lane xors (q = l16; quads hold different keys)
      f32x4 vm;
#pragma unroll
      for (int r = 0; r < 4; ++r)
        vm[r] = fmaxf(fmaxf(s[mt][0][r], s[mt][1][r]), fmaxf(s[mt][2][r], s[mt][3][r]));
      float mx = fmaxf(fmaxf(vm[0], vm[1]), fmaxf(vm[2], vm[3]));
      mx = fmaxf(mx, __shfl_xor(mx, 16));
      mx = fmaxf(mx, __shfl_xor(mx, 32));
      // defer-max (T13): only rescale when the tile max grew past THR=8 (log2 units; P <= 2^8)
      if (!__all(mx <= mst[mt] + 8.0f)) {
        float nm = fmaxf(mst[mt], mx);
        float al = __builtin_amdgcn_exp2f(mst[mt] - nm);
        mst[mt] = nm;
        Lacc[mt] *= al;
#pragma unroll
        for (int dt = 0; dt < 8; ++dt) O[mt][dt] *= al;
      }
      // P = exp2(S^T - m) -> bf16 B-fragments (truncating cvt), directly in registers
#pragma unroll
      for (int nt = 0; nt < 4; ++nt) {
        bf16x4 p;
#pragma unroll
        for (int r = 0; r < 4; ++r) p[r] = f2bf_t(__builtin_amdgcn_exp2f(s[mt][nt][r] - mst[mt]));
        pb[mt][nt] = p;
      }
    }
    // O^T += V^T·P^T ; Lacc += 1·P^T   (16x16x16, k=16 keys per step)
    // A-fragment av[dt] = V^T[dt*16+l16][jt*64 + nt*16 + quad*4 ..+3] read direct from global.
    const short* vrow = vlane + (long)jt * 64;
#pragma unroll
    for (int nt = 0; nt < 4; ++nt) {
      bf16x4 av[8];
#pragma unroll
      for (int dt = 0; dt < 8; ++dt) av[dt] = *(const bf16x4*)&vrow[(long)dt * 16 * 2048 + nt * 16];
#pragma unroll
      for (int mt = 0; mt < 2; ++mt) {
#pragma unroll
        for (int dt = 0; dt < 8; ++dt)
          O[mt][dt] = __builtin_amdgcn_mfma_f32_16x16x16bf16_1k(av[dt], pb[mt][nt], O[mt][dt], 0, 0, 0);
        Lacc[mt] = __builtin_amdgcn_mfma_f32_16x16x16bf16_1k(ones4, pb[mt][nt], Lacc[mt], 0, 0, 0);
      }
    }
  }
#undef STAGE
  // epilogue: y[q][h*128+d] = O^T[d][q] / l[q]; lane writes 4 consecutive d per (mt,dt)
#pragma unroll
  for (int mt = 0; mt < 2; ++mt) {
    float inv = __builtin_amdgcn_rcpf(Lacc[mt][0]);
    int q = qt * 64 + w * 32 + mt * 16 + l16;
#pragma unroll
    for (int dt = 0; dt < 8; ++dt) {
      short4 s4;
      s4.x = f2bf(O[mt][dt][0] * inv);
      s4.y = f2bf(O[mt][dt][1] * inv);
      s4.z = f2bf(O[mt][dt][2] * inv);
      s4.w = f2bf(O[mt][dt][3] * inv);
      *(short4*)&y[((long)(b * 2048 + q)) * 2048 + h * 128 + dt * 16 + quad * 4] = s4;
    }
  }
}

extern "C" void kernel_launch(void* const* d_in, const int* in_sizes, int n_in,
                              void* d_out, int out_size, void* d_ws, size_t ws_size,
                              hipStream_t stream) {
  const float* x       = (const float*)d_in[0];
  const float* diag    = (const float*)d_in[1];
  const float* left_w  = (const float*)d_in[2];
  const float* right_w = (const float*)d_in[3];
  const float* right_b = (const float*)d_in[4];
  const float* bias_p  = (const float*)d_in[5];
  float* out = (float*)d_out;

  char* ws = (char*)d_ws;
  short* xb = (short*)(ws + 0);              // 33,554,432 B  (aliased as y after attention)
  short* LT = (short*)(ws + 33554432);       //  2,097,152 B
  short* WT = (short*)(ws + 35651584);       //  4,194,304 B
  short* xl = (short*)(ws + 39845888);       //  6,291,456 B
  short* yl = (short*)(ws + 46137344);       //  2,097,152 B
  short* qb = (short*)(ws + 48234496);       // 33,554,432 B
  short* kb = (short*)(ws + 81788928);       // 33,554,432 B
  short* vT = (short*)(ws + 115343360);      // 33,554,432 B
  short* y  = xb;

  cast_prep_kernel<<<28672, 256, 0, stream>>>(x, left_w, diag, right_w, xb, LT, WT);
  gemm_bt<<<dim3(256, 3), 256, 0, stream>>>(xb, LT, xl, 8192, 384, 2048);
  lori_gemm<<<dim3(64, 48), 256, 0, stream>>>(xb, xl, 384, WT, right_b, bias_p, 0, qb, kb, vT, nullptr);
  attn_kernel<<<dim3(2048), 128, 0, stream>>>(qb, kb, vT, y);
  gemm_bt<<<dim3(256, 1), 256, 0, stream>>>(y, LT + 3L * 128 * 2048, yl, 8192, 128, 2048);
  lori_gemm<<<dim3(64, 16), 256, 0, stream>>>(y, yl, 128, WT, right_b, bias_p, 3, nullptr, nullptr, nullptr, out);
}

// Round 10
// 656.870 us; speedup vs baseline: 1.2605x; 1.2605x over previous
//
#include <hip/hip_runtime.h>

typedef short bf16x8 __attribute__((ext_vector_type(8)));
typedef short bf16x4 __attribute__((ext_vector_type(4)));
typedef float f32x4  __attribute__((ext_vector_type(4)));

#define AS1 __attribute__((address_space(1)))
#define AS3 __attribute__((address_space(3)))

__device__ __forceinline__ void gload16(const void* g, void* l) {
  __builtin_amdgcn_global_load_lds((const AS1 void*)g, (AS3 void*)l, 16, 0, 0);
}

__device__ __forceinline__ short f2bf(float f) {
  union { float fv; unsigned u; } v; v.fv = f;
  unsigned r = v.u + 0x7fffu + ((v.u >> 16) & 1u);
  return (short)(r >> 16);
}

// truncating f32->bf16 (P in (0,256]; numerator & denominator share P so bias cancels)
__device__ __forceinline__ short f2bf_t(float f) {
  return (short)(__float_as_uint(f) >> 16);
}

// ---------------- fused cast x (fp32->bf16, float4/thread) + weight prep ----------------
__global__ void cast_prep_kernel(const float* __restrict__ x, const float* __restrict__ left_w,
                                 const float* __restrict__ diag, const float* __restrict__ right_w,
                                 short* __restrict__ xb, short* __restrict__ LT, short* __restrict__ WT) {
  long idx = (long)blockIdx.x * 256 + threadIdx.x;
  const long N4 = 4194304L;              // x elements / 4
  const long LTN = 4L * 128 * 2048;
  const long WTN = 4L * 16 * 128 * 256;
  if (idx < N4) {
    float4 v = ((const float4*)x)[idx];
    short4 s;
    s.x = f2bf(v.x); s.y = f2bf(v.y); s.z = f2bf(v.z); s.w = f2bf(v.w);
    ((short4*)xb)[idx] = s;
  } else if (idx < N4 + LTN) {
    long j = idx - N4;
    LT[j] = f2bf(left_w[j]);
  } else if (idx < N4 + LTN + WTN) {
    long j = idx - N4 - LTN;
    int d = (int)(j & 255);
    long rest = j >> 8;
    int e = (int)(rest & 127);
    long gi = rest >> 7;
    int i = (int)(gi >> 4), n = (int)(gi & 15);
    float v;
    if (d < 128) v = diag[(gi * 128 + d) * 128 + e];
    else         v = right_w[((long)i * 2048 + n * 128 + e) * 128 + (d - 128)];
    WT[j] = f2bf(v);
  }
}

// ---------------- 32x128-tile GEMM, double-buffered K (XOR-swizzled LDS): C = A @ BT^T ----------------
// Thin-N variant: M-tile 32, N-tile 128 -> grid (M/32, N/128). 4 waves, each 32(M)x32(N), acc[2][2].
__global__ __launch_bounds__(256) void gemm_bt(const short* __restrict__ A, const short* __restrict__ BT,
                                               short* __restrict__ C, int M, int N, int K) {
  __shared__ __align__(16) short As[2][32 * 64];    // 4KB per buf
  __shared__ __align__(16) short Bs[2][128 * 64];   // 16KB per buf
  int tid = threadIdx.x, w = tid >> 6, lane = tid & 63;
  int m0 = blockIdx.x * 32, n0 = blockIdx.y * 128;
  int wn = w * 32;
  int quad = lane >> 4, l16 = lane & 15;
  int srow = lane >> 3;
  int schunk = ((lane & 7) ^ srow) * 8;   // XOR-swizzled source chunk (matches read-side l16&7 XOR)

#define GSTAGE(K0, BUF) {                                                             \
    gload16(&A[(long)(m0 + w * 8 + srow) * K + (K0) + schunk], &As[BUF][(w * 8) * 64]); \
    for (int p = 0; p < 4; ++p) {                                                     \
      int r = p * 32 + w * 8 + srow;                                                  \
      gload16(&BT[(long)(n0 + r) * K + (K0) + schunk], &Bs[BUF][(p * 32 + w * 8) * 64]); \
    }                                                                                 \
  }

  f32x4 acc[2][2] = {};
  GSTAGE(0, 0)
  __syncthreads();
  int nk = K >> 6;
  for (int it = 0; it < nk; ++it) {
    int cur = it & 1;
    if (it + 1 < nk) GSTAGE((it + 1) * 64, cur ^ 1)   // prefetch overlaps compute
#pragma unroll
    for (int kk = 0; kk < 2; ++kk) {
      int c = (((kk * 4 + quad) ^ (l16 & 7)) * 8);
      bf16x8 a[2], b[2];
#pragma unroll
      for (int t = 0; t < 2; ++t) a[t] = *(const bf16x8*)&As[cur][(t * 16 + l16) * 64 + c];
#pragma unroll
      for (int t = 0; t < 2; ++t) b[t] = *(const bf16x8*)&Bs[cur][(wn + t * 16 + l16) * 64 + c];
#pragma unroll
      for (int mt = 0; mt < 2; ++mt)
#pragma unroll
        for (int nt = 0; nt < 2; ++nt)
          acc[mt][nt] = __builtin_amdgcn_mfma_f32_16x16x32_bf16(a[mt], b[nt], acc[mt][nt], 0, 0, 0);
    }
    __syncthreads();
  }
#undef GSTAGE
#pragma unroll
  for (int mt = 0; mt < 2; ++mt)
#pragma unroll
    for (int nt = 0; nt < 2; ++nt)
#pragma unroll
      for (int r = 0; r < 4; ++r) {
        int m = m0 + mt * 16 + quad * 4 + r;
        int n = n0 + wn + nt * 16 + l16;
        C[(long)m * N + n] = f2bf(acc[mt][nt][r]);
      }
}

// ---------------- grouped lori GEMM, double-buffered kt (XOR-swizzled LDS) ----------------
__global__ __launch_bounds__(256) void lori_gemm(const short* __restrict__ tok, const short* __restrict__ rnk,
                                                 int rstride, const short* __restrict__ WT,
                                                 const float* __restrict__ rb, const float* __restrict__ bp,
                                                 int i_base, short* __restrict__ qb, short* __restrict__ kb,
                                                 short* __restrict__ vT, float* __restrict__ out) {
  __shared__ __align__(16) short As[2][128 * 64];
  __shared__ __align__(16) short Bs[2][128 * 64];
  int tid = threadIdx.x, w = tid >> 6, lane = tid & 63;
  int i = i_base + (blockIdx.y >> 4);
  int n = blockIdx.y & 15;
  int t0 = blockIdx.x * 128;
  int co = (i < 3) ? i * 128 : 0;
  const short* WTn = WT + (long)(i * 16 + n) * 128 * 256;
  int wm = (w >> 1) * 64, wn = (w & 1) * 64;
  int quad = lane >> 4, l16 = lane & 15;
  int srow = lane >> 3;
  int schunk = ((lane & 7) ^ srow) * 8;

#define LSTAGE(KT, BUF) {                                                             \
    for (int p = 0; p < 4; ++p) {                                                     \
      int r = p * 32 + w * 8 + srow;                                                  \
      const short* ga;                                                                \
      if ((KT) < 2) ga = &tok[(long)(t0 + r) * 2048 + n * 128 + (KT) * 64 + schunk];  \
      else          ga = &rnk[(long)(t0 + r) * rstride + co + ((KT) - 2) * 64 + schunk]; \
      gload16(ga, &As[BUF][(p * 32 + w * 8) * 64]);                                   \
      gload16(&WTn[r * 256 + (KT) * 64 + schunk], &Bs[BUF][(p * 32 + w * 8) * 64]);   \
    }                                                                                 \
  }

  f32x4 acc[4][4] = {};
  LSTAGE(0, 0)
  __syncthreads();
#pragma unroll
  for (int kt = 0; kt < 4; ++kt) {
    int cur = kt & 1;
    if (kt < 3) LSTAGE(kt + 1, cur ^ 1)   // prefetch overlaps compute
#pragma unroll
    for (int kk = 0; kk < 2; ++kk) {
      int c = (((kk * 4 + quad) ^ (l16 & 7)) * 8);
      bf16x8 a[4], b[4];
#pragma unroll
      for (int t = 0; t < 4; ++t) a[t] = *(const bf16x8*)&As[cur][(wm + t * 16 + l16) * 64 + c];
#pragma unroll
      for (int t = 0; t < 4; ++t) b[t] = *(const bf16x8*)&Bs[cur][(wn + t * 16 + l16) * 64 + c];
#pragma unroll
      for (int mt = 0; mt < 4; ++mt)
#pragma unroll
        for (int nt = 0; nt < 4; ++nt)
          acc[mt][nt] = __builtin_amdgcn_mfma_f32_16x16x32_bf16(a[mt], b[nt], acc[mt][nt], 0, 0, 0);
    }
    __syncthreads();
  }
#undef LSTAGE
  int b = t0 >> 11;
  int tl0 = t0 & 2047;
  const float QSC = 0.08838834764831845f * 1.4426950408889634f;  // 1/sqrt(128) * log2(e)
#pragma unroll
  for (int mt = 0; mt < 4; ++mt) {
#pragma unroll
    for (int nt = 0; nt < 4; ++nt) {
      int e = wn + nt * 16 + l16;
      int c = n * 128 + e;
      float bias = rb[i * 2048 + c] + bp[i * 2048 + c];
      int tl = tl0 + wm + mt * 16 + quad * 4;
      if (i == 0) {
#pragma unroll
        for (int r = 0; r < 4; ++r)
          qb[((long)(b * 16 + n) * 2048 + tl + r) * 128 + e] = f2bf((acc[mt][nt][r] + bias) * QSC);
      } else if (i == 1) {
#pragma unroll
        for (int r = 0; r < 4; ++r)
          kb[((long)(b * 16 + n) * 2048 + tl + r) * 128 + e] = f2bf(acc[mt][nt][r] + bias);
      } else if (i == 2) {
        short4 s4;
        s4.x = f2bf(acc[mt][nt][0] + bias);
        s4.y = f2bf(acc[mt][nt][1] + bias);
        s4.z = f2bf(acc[mt][nt][2] + bias);
        s4.w = f2bf(acc[mt][nt][3] + bias);
        *(short4*)&vT[((long)(b * 16 + n) * 128 + e) * 2048 + tl] = s4;
      } else {
#pragma unroll
        for (int r = 0; r < 4; ++r)
          out[(long)(t0 + wm + mt * 16 + quad * 4 + r) * 2048 + c] = acc[mt][nt][r] + bias;
      }
    }
  }
}

// ---------------- flash attention v13b: direct-V (no V-LDS), 16KB LDS, launch_bounds(128,3) ----------------
// Round 9's (128,4) capped regs at 128 -> allocator collapsed to 64 VGPR + scratch spill
// (FETCH 810MB / WRITE 713MB). (128,3) gives ~170-reg budget (held 104 spill-free in v12).
// Registers then bind at 3 waves/SIMD -> 6 blocks/CU (12 waves), +20% over v12, AND:
//   - SQ_LDS_BANK_CONFLICT drops 8.65M -> 0 (proven in round 9: the vs read was the source)
//   - STAGE halves (K only) -> half the vmcnt drain per barrier
// vT[bh][d][t] is already in PV's consumption layout; V fragments read direct from global
// (L2/L3-resident, ~11 TB/s aggregate vs 34.5 TB/s L2 ceiling).
// grid: 2048 = 64 bh x 32 q-tiles (64 rows each); long q-tiles dispatched first.
__global__ __launch_bounds__(128, 3) void attn_kernel(const short* __restrict__ qb, const short* __restrict__ kb,
                                                      const short* __restrict__ vT, short* __restrict__ y) {
  __shared__ __align__(16) short ks[64 * 128];   // K tile, 16-chunk XOR swizzle per row (16KB)
  int tid = threadIdx.x, w = tid >> 6, lane = tid & 63;
  int id = blockIdx.x;
  int bh = id & 63;                   // bh&7 = XCD pin for K/V L2 locality
  int qt = 31 - (id >> 6);            // q-tile (64 rows); long tiles first
  int b = bh >> 4, h = bh & 15;
  int quad = lane >> 4, l16 = lane & 15;

  // Q fragments global->VGPR; serve as B-operand (k=d=quad*8+j, n=q=l16) of S^T MFMA
  bf16x8 aq[2][4];
#pragma unroll
  for (int mt = 0; mt < 2; ++mt)
#pragma unroll
    for (int kk = 0; kk < 4; ++kk)
      aq[mt][kk] = *(const bf16x8*)&qb[((long)bh * 2048 + qt * 64 + w * 32 + mt * 16 + l16) * 128 + kk * 32 + quad * 8];

  f32x4 O[2][8] = {};                 // O^T tiles: row=d (quad*4+r within dt), col=q (l16)
  f32x4 Lacc[2] = {};                 // ones-MFMA row-sum accumulator (rows identical)
  float mst[2] = {-3.0e38f, -3.0e38f};
  const bf16x4 ones4 = {(short)0x3F80, (short)0x3F80, (short)0x3F80, (short)0x3F80};

  // staging lane constants (K only; V is read direct from global)
  int kq = lane >> 4;

  const short* kbase = kb + (long)bh * 2048 * 128;
  const short* vbase = vT + (long)bh * 128 * 2048;
  const short* vlane = vbase + (long)l16 * 2048 + quad * 4;   // + dt*16*2048 + jt*64 + nt*16 at use

  // stage split across 2 waves: wave w loads K rows w*32..w*32+31 (4 rows/instr, 8 instrs).
  // Swizzle identity preserved: (w*32+p*4+kq)&15 == (p*4+kq)&15.
#define STAGE(JT) {                                                                   \
    for (int p = 0; p < 8; ++p) {                                                     \
      int r = w * 32 + p * 4 + kq;                                                    \
      int kch = l16 ^ ((p * 4 + kq) & 15);                                            \
      gload16(&kbase[((long)((JT) * 64 + r)) * 128 + kch * 8], &ks[(w * 32 + p * 4) * 128]); \
    }                                                                                 \
  }

  for (int jt = 0; jt <= qt; ++jt) {
    if (jt) __syncthreads();          // both waves done reading previous tile
    STAGE(jt)
    __syncthreads();                  // stage landed (vmcnt drain folded in)

    // S^T = K·Q^T  (wave: 64 keys x 32 q)
    f32x4 s[2][4] = {};
#pragma unroll
    for (int nt = 0; nt < 4; ++nt)
#pragma unroll
      for (int kk = 0; kk < 4; ++kk) {
        bf16x8 bk = *(const bf16x8*)&ks[(nt * 16 + l16) * 128 + (((kk * 4 + quad) ^ l16) * 8)];
        s[0][nt] = __builtin_amdgcn_mfma_f32_16x16x32_bf16(bk, aq[0][kk], s[0][nt], 0, 0, 0);
        s[1][nt] = __builtin_amdgcn_mfma_f32_16x16x32_bf16(bk, aq[1][kk], s[1][nt], 0, 0, 0);
      }
    if (jt == qt) {   // diagonal tile: causal mask
#pragma unroll
      for (int mt = 0; mt < 2; ++mt)
#pragma unroll
        for (int nt = 0; nt < 4; ++nt) {
          int q = qt * 64 + w * 32 + mt * 16 + l16;
#pragma unroll
          for (int r = 0; r < 4; ++r) {
            int key = jt * 64 + nt * 16 + quad * 4 + r;
            if (key > q) s[mt][nt][r] = -3.0e38f;
          }
        }
    }
    bf16x4 pb[2][4];
#pragma unroll
    for (int mt = 0; mt < 2; ++mt) {
      // per-q max: in-register tree + 2 cross-lane xors (q = l16; quads hold different keys)
      f32x4 vm;
#pragma unroll
      for (int r = 0; r < 4; ++r)
        vm[r] = fmaxf(fmaxf(s[mt][0][r], s[mt][1][r]), fmaxf(s[mt][2][r], s[mt][3][r]));
      float mx = fmaxf(fmaxf(vm[0], vm[1]), fmaxf(vm[2], vm[3]));
      mx = fmaxf(mx, __shfl_xor(mx, 16));
      mx = fmaxf(mx, __shfl_xor(mx, 32));
      // defer-max (T13): only rescale when the tile max grew past THR=8 (log2 units; P <= 2^8)
      if (!__all(mx <= mst[mt] + 8.0f)) {
        float nm = fmaxf(mst[mt], mx);
        float al = __builtin_amdgcn_exp2f(mst[mt] - nm);
        mst[mt] = nm;
        Lacc[mt] *= al;
#pragma unroll
        for (int dt = 0; dt < 8; ++dt) O[mt][dt] *= al;
      }
      // P = exp2(S^T - m) -> bf16 B-fragments (truncating cvt), directly in registers
#pragma unroll
      for (int nt = 0; nt < 4; ++nt) {
        bf16x4 p;
#pragma unroll
        for (int r = 0; r < 4; ++r) p[r] = f2bf_t(__builtin_amdgcn_exp2f(s[mt][nt][r] - mst[mt]));
        pb[mt][nt] = p;
      }
    }
    // O^T += V^T·P^T ; Lacc += 1·P^T   (16x16x16, k=16 keys per step)
    // A-fragment av[dt] = V^T[dt*16+l16][jt*64 + nt*16 + quad*4 ..+3] read direct from global.
    const short* vrow = vlane + (long)jt * 64;
#pragma unroll
    for (int nt = 0; nt < 4; ++nt) {
      bf16x4 av[8];
#pragma unroll
      for (int dt = 0; dt < 8; ++dt) av[dt] = *(const bf16x4*)&vrow[(long)dt * 16 * 2048 + nt * 16];
#pragma unroll
      for (int mt = 0; mt < 2; ++mt) {
#pragma unroll
        for (int dt = 0; dt < 8; ++dt)
          O[mt][dt] = __builtin_amdgcn_mfma_f32_16x16x16bf16_1k(av[dt], pb[mt][nt], O[mt][dt], 0, 0, 0);
        Lacc[mt] = __builtin_amdgcn_mfma_f32_16x16x16bf16_1k(ones4, pb[mt][nt], Lacc[mt], 0, 0, 0);
      }
    }
  }
#undef STAGE
  // epilogue: y[q][h*128+d] = O^T[d][q] / l[q]; lane writes 4 consecutive d per (mt,dt)
#pragma unroll
  for (int mt = 0; mt < 2; ++mt) {
    float inv = __builtin_amdgcn_rcpf(Lacc[mt][0]);
    int q = qt * 64 + w * 32 + mt * 16 + l16;
#pragma unroll
    for (int dt = 0; dt < 8; ++dt) {
      short4 s4;
      s4.x = f2bf(O[mt][dt][0] * inv);
      s4.y = f2bf(O[mt][dt][1] * inv);
      s4.z = f2bf(O[mt][dt][2] * inv);
      s4.w = f2bf(O[mt][dt][3] * inv);
      *(short4*)&y[((long)(b * 2048 + q)) * 2048 + h * 128 + dt * 16 + quad * 4] = s4;
    }
  }
}

extern "C" void kernel_launch(void* const* d_in, const int* in_sizes, int n_in,
                              void* d_out, int out_size, void* d_ws, size_t ws_size,
                              hipStream_t stream) {
  const float* x       = (const float*)d_in[0];
  const float* diag    = (const float*)d_in[1];
  const float* left_w  = (const float*)d_in[2];
  const float* right_w = (const float*)d_in[3];
  const float* right_b = (const float*)d_in[4];
  const float* bias_p  = (const float*)d_in[5];
  float* out = (float*)d_out;

  char* ws = (char*)d_ws;
  short* xb = (short*)(ws + 0);              // 33,554,432 B  (aliased as y after attention)
  short* LT = (short*)(ws + 33554432);       //  2,097,152 B
  short* WT = (short*)(ws + 35651584);       //  4,194,304 B
  short* xl = (short*)(ws + 39845888);       //  6,291,456 B
  short* yl = (short*)(ws + 46137344);       //  2,097,152 B
  short* qb = (short*)(ws + 48234496);       // 33,554,432 B
  short* kb = (short*)(ws + 81788928);       // 33,554,432 B
  short* vT = (short*)(ws + 115343360);      // 33,554,432 B
  short* y  = xb;

  cast_prep_kernel<<<28672, 256, 0, stream>>>(x, left_w, diag, right_w, xb, LT, WT);
  gemm_bt<<<dim3(256, 3), 256, 0, stream>>>(xb, LT, xl, 8192, 384, 2048);
  lori_gemm<<<dim3(64, 48), 256, 0, stream>>>(xb, xl, 384, WT, right_b, bias_p, 0, qb, kb, vT, nullptr);
  attn_kernel<<<dim3(2048), 128, 0, stream>>>(qb, kb, vT, y);
  gemm_bt<<<dim3(256, 1), 256, 0, stream>>>(y, LT + 3L * 128 * 2048, yl, 8192, 128, 2048);
  lori_gemm<<<dim3(64, 16), 256, 0, stream>>>(y, yl, 128, WT, right_b, bias_p, 3, nullptr, nullptr, nullptr, out);
}

// Round 11
// 383.710 us; speedup vs baseline: 2.1579x; 1.7119x over previous
//
#include <hip/hip_runtime.h>

typedef short bf16x8 __attribute__((ext_vector_type(8)));
typedef short bf16x4 __attribute__((ext_vector_type(4)));
typedef float f32x4  __attribute__((ext_vector_type(4)));

#define AS1 __attribute__((address_space(1)))
#define AS3 __attribute__((address_space(3)))

__device__ __forceinline__ void gload16(const void* g, void* l) {
  __builtin_amdgcn_global_load_lds((const AS1 void*)g, (AS3 void*)l, 16, 0, 0);
}

__device__ __forceinline__ short f2bf(float f) {
  union { float fv; unsigned u; } v; v.fv = f;
  unsigned r = v.u + 0x7fffu + ((v.u >> 16) & 1u);
  return (short)(r >> 16);
}

// truncating f32->bf16 (P in (0,256]; numerator & denominator share P so bias cancels)
__device__ __forceinline__ short f2bf_t(float f) {
  return (short)(__float_as_uint(f) >> 16);
}

// ---------------- fused cast x (fp32->bf16, float4/thread) + weight prep ----------------
__global__ void cast_prep_kernel(const float* __restrict__ x, const float* __restrict__ left_w,
                                 const float* __restrict__ diag, const float* __restrict__ right_w,
                                 short* __restrict__ xb, short* __restrict__ LT, short* __restrict__ WT) {
  long idx = (long)blockIdx.x * 256 + threadIdx.x;
  const long N4 = 4194304L;              // x elements / 4
  const long LTN = 4L * 128 * 2048;
  const long WTN = 4L * 16 * 128 * 256;
  if (idx < N4) {
    float4 v = ((const float4*)x)[idx];
    short4 s;
    s.x = f2bf(v.x); s.y = f2bf(v.y); s.z = f2bf(v.z); s.w = f2bf(v.w);
    ((short4*)xb)[idx] = s;
  } else if (idx < N4 + LTN) {
    long j = idx - N4;
    LT[j] = f2bf(left_w[j]);
  } else if (idx < N4 + LTN + WTN) {
    long j = idx - N4 - LTN;
    int d = (int)(j & 255);
    long rest = j >> 8;
    int e = (int)(rest & 127);
    long gi = rest >> 7;
    int i = (int)(gi >> 4), n = (int)(gi & 15);
    float v;
    if (d < 128) v = diag[(gi * 128 + d) * 128 + e];
    else         v = right_w[((long)i * 2048 + n * 128 + e) * 128 + (d - 128)];
    WT[j] = f2bf(v);
  }
}

// ---------------- 32x128-tile GEMM, double-buffered K (XOR-swizzled LDS): C = A @ BT^T ----------------
// Thin-N variant: M-tile 32, N-tile 128 -> grid (M/32, N/128). 4 waves, each 32(M)x32(N), acc[2][2].
// K=2048 (32 iters): prefetch double-buffer pays here; 40KB LDS -> 4 blocks/CU already.
__global__ __launch_bounds__(256) void gemm_bt(const short* __restrict__ A, const short* __restrict__ BT,
                                               short* __restrict__ C, int M, int N, int K) {
  __shared__ __align__(16) short As[2][32 * 64];    // 4KB per buf
  __shared__ __align__(16) short Bs[2][128 * 64];   // 16KB per buf
  int tid = threadIdx.x, w = tid >> 6, lane = tid & 63;
  int m0 = blockIdx.x * 32, n0 = blockIdx.y * 128;
  int wn = w * 32;
  int quad = lane >> 4, l16 = lane & 15;
  int srow = lane >> 3;
  int schunk = ((lane & 7) ^ srow) * 8;   // XOR-swizzled source chunk (matches read-side l16&7 XOR)

#define GSTAGE(K0, BUF) {                                                             \
    gload16(&A[(long)(m0 + w * 8 + srow) * K + (K0) + schunk], &As[BUF][(w * 8) * 64]); \
    for (int p = 0; p < 4; ++p) {                                                     \
      int r = p * 32 + w * 8 + srow;                                                  \
      gload16(&BT[(long)(n0 + r) * K + (K0) + schunk], &Bs[BUF][(p * 32 + w * 8) * 64]); \
    }                                                                                 \
  }

  f32x4 acc[2][2] = {};
  GSTAGE(0, 0)
  __syncthreads();
  int nk = K >> 6;
  for (int it = 0; it < nk; ++it) {
    int cur = it & 1;
    if (it + 1 < nk) GSTAGE((it + 1) * 64, cur ^ 1)   // prefetch overlaps compute
#pragma unroll
    for (int kk = 0; kk < 2; ++kk) {
      int c = (((kk * 4 + quad) ^ (l16 & 7)) * 8);
      bf16x8 a[2], b[2];
#pragma unroll
      for (int t = 0; t < 2; ++t) a[t] = *(const bf16x8*)&As[cur][(t * 16 + l16) * 64 + c];
#pragma unroll
      for (int t = 0; t < 2; ++t) b[t] = *(const bf16x8*)&Bs[cur][(wn + t * 16 + l16) * 64 + c];
#pragma unroll
      for (int mt = 0; mt < 2; ++mt)
#pragma unroll
        for (int nt = 0; nt < 2; ++nt)
          acc[mt][nt] = __builtin_amdgcn_mfma_f32_16x16x32_bf16(a[mt], b[nt], acc[mt][nt], 0, 0, 0);
    }
    __syncthreads();
  }
#undef GSTAGE
#pragma unroll
  for (int mt = 0; mt < 2; ++mt)
#pragma unroll
    for (int nt = 0; nt < 2; ++nt)
#pragma unroll
      for (int r = 0; r < 4; ++r) {
        int m = m0 + mt * 16 + quad * 4 + r;
        int n = n0 + wn + nt * 16 + l16;
        C[(long)m * N + n] = f2bf(acc[mt][nt][r]);
      }
}

// ---------------- grouped lori GEMM, SINGLE-buffered kt (XOR-swizzled LDS), 32KB LDS ----------------
// K=256 (4 kt steps): prefetch double-buffer bought little but halved residency (64KB -> 2 blk/CU,
// the barrier phase-correlated regime round 6 proved costly). Single-buffer: 32KB -> ~4 blocks/CU
// (register-bound), 2 barriers/kt. Same v11/v12 decorrelation lever applied to the GEMM side.
__global__ __launch_bounds__(256) void lori_gemm(const short* __restrict__ tok, const short* __restrict__ rnk,
                                                 int rstride, const short* __restrict__ WT,
                                                 const float* __restrict__ rb, const float* __restrict__ bp,
                                                 int i_base, short* __restrict__ qb, short* __restrict__ kb,
                                                 short* __restrict__ vT, float* __restrict__ out) {
  __shared__ __align__(16) short As[128 * 64];   // 16KB
  __shared__ __align__(16) short Bs[128 * 64];   // 16KB
  int tid = threadIdx.x, w = tid >> 6, lane = tid & 63;
  int i = i_base + (blockIdx.y >> 4);
  int n = blockIdx.y & 15;
  int t0 = blockIdx.x * 128;
  int co = (i < 3) ? i * 128 : 0;
  const short* WTn = WT + (long)(i * 16 + n) * 128 * 256;
  int wm = (w >> 1) * 64, wn = (w & 1) * 64;
  int quad = lane >> 4, l16 = lane & 15;
  int srow = lane >> 3;
  int schunk = ((lane & 7) ^ srow) * 8;

#define LSTAGE(KT) {                                                                  \
    for (int p = 0; p < 4; ++p) {                                                     \
      int r = p * 32 + w * 8 + srow;                                                  \
      const short* ga;                                                                \
      if ((KT) < 2) ga = &tok[(long)(t0 + r) * 2048 + n * 128 + (KT) * 64 + schunk];  \
      else          ga = &rnk[(long)(t0 + r) * rstride + co + ((KT) - 2) * 64 + schunk]; \
      gload16(ga, &As[(p * 32 + w * 8) * 64]);                                        \
      gload16(&WTn[r * 256 + (KT) * 64 + schunk], &Bs[(p * 32 + w * 8) * 64]);        \
    }                                                                                 \
  }

  f32x4 acc[4][4] = {};
#pragma unroll
  for (int kt = 0; kt < 4; ++kt) {
    if (kt) __syncthreads();          // all waves done reading previous kt
    LSTAGE(kt)
    __syncthreads();                  // stage landed (vmcnt drain folded in)
#pragma unroll
    for (int kk = 0; kk < 2; ++kk) {
      int c = (((kk * 4 + quad) ^ (l16 & 7)) * 8);
      bf16x8 a[4], b[4];
#pragma unroll
      for (int t = 0; t < 4; ++t) a[t] = *(const bf16x8*)&As[(wm + t * 16 + l16) * 64 + c];
#pragma unroll
      for (int t = 0; t < 4; ++t) b[t] = *(const bf16x8*)&Bs[(wn + t * 16 + l16) * 64 + c];
#pragma unroll
      for (int mt = 0; mt < 4; ++mt)
#pragma unroll
        for (int nt = 0; nt < 4; ++nt)
          acc[mt][nt] = __builtin_amdgcn_mfma_f32_16x16x32_bf16(a[mt], b[nt], acc[mt][nt], 0, 0, 0);
    }
  }
#undef LSTAGE
  int b = t0 >> 11;
  int tl0 = t0 & 2047;
  const float QSC = 0.08838834764831845f * 1.4426950408889634f;  // 1/sqrt(128) * log2(e)
#pragma unroll
  for (int mt = 0; mt < 4; ++mt) {
#pragma unroll
    for (int nt = 0; nt < 4; ++nt) {
      int e = wn + nt * 16 + l16;
      int c = n * 128 + e;
      float bias = rb[i * 2048 + c] + bp[i * 2048 + c];
      int tl = tl0 + wm + mt * 16 + quad * 4;
      if (i == 0) {
#pragma unroll
        for (int r = 0; r < 4; ++r)
          qb[((long)(b * 16 + n) * 2048 + tl + r) * 128 + e] = f2bf((acc[mt][nt][r] + bias) * QSC);
      } else if (i == 1) {
#pragma unroll
        for (int r = 0; r < 4; ++r)
          kb[((long)(b * 16 + n) * 2048 + tl + r) * 128 + e] = f2bf(acc[mt][nt][r] + bias);
      } else if (i == 2) {
        short4 s4;
        s4.x = f2bf(acc[mt][nt][0] + bias);
        s4.y = f2bf(acc[mt][nt][1] + bias);
        s4.z = f2bf(acc[mt][nt][2] + bias);
        s4.w = f2bf(acc[mt][nt][3] + bias);
        *(short4*)&vT[((long)(b * 16 + n) * 128 + e) * 2048 + tl] = s4;
      } else {
#pragma unroll
        for (int r = 0; r < 4; ++r)
          out[(long)(t0 + wm + mt * 16 + quad * 4 + r) * 2048 + c] = acc[mt][nt][r] + bias;
      }
    }
  }
}

// ---------------- flash attention v12 (RESTORED): 2-wave blocks, 64-row q tile, 5 blocks/CU ----------------
// Round 10 refuted direct-V: FETCH 79->481MB (scattered 8B V-loads thrash the 4MB/XCD L2; the
// LDS staging was a latency firewall + coalescer, not a relay). v12 = best verified: attn 122us.
// qb,kb: [bh][t][d] bf16 (q pre-scaled by log2e/sqrt(128)); vT: [bh][d][t]; y: [b][t][h*128+d]
// grid: 2048 = 64 bh x 32 q-tiles (64 rows each); long q-tiles dispatched first.
__global__ __launch_bounds__(128, 2) void attn_kernel(const short* __restrict__ qb, const short* __restrict__ kb,
                                                      const short* __restrict__ vT, short* __restrict__ y) {
  __shared__ __align__(16) short ks[64 * 128];   // K tile, 16-chunk XOR swizzle per row (16KB)
  __shared__ __align__(16) short vs[128 * 64];   // V^T tile, 8-chunk XOR swizzle per row (16KB)
  int tid = threadIdx.x, w = tid >> 6, lane = tid & 63;
  int id = blockIdx.x;
  int bh = id & 63;                   // bh&7 = XCD pin for K/V L2 locality
  int qt = 31 - (id >> 6);            // q-tile (64 rows); long tiles first
  int b = bh >> 4, h = bh & 15;
  int quad = lane >> 4, l16 = lane & 15;

  // Q fragments global->VGPR; serve as B-operand (k=d=quad*8+j, n=q=l16) of S^T MFMA
  bf16x8 aq[2][4];
#pragma unroll
  for (int mt = 0; mt < 2; ++mt)
#pragma unroll
    for (int kk = 0; kk < 4; ++kk)
      aq[mt][kk] = *(const bf16x8*)&qb[((long)bh * 2048 + qt * 64 + w * 32 + mt * 16 + l16) * 128 + kk * 32 + quad * 8];

  f32x4 O[2][8] = {};                 // O^T tiles: row=d (quad*4+r within dt), col=q (l16)
  f32x4 Lacc[2] = {};                 // ones-MFMA row-sum accumulator (rows identical)
  float mst[2] = {-3.0e38f, -3.0e38f};
  const bf16x4 ones4 = {(short)0x3F80, (short)0x3F80, (short)0x3F80, (short)0x3F80};

  // staging lane constants
  int kq = lane >> 4;
  int vrow8 = lane >> 3;
  int vchunk = (lane & 7) ^ (vrow8 & 7);

  const short* kbase = kb + (long)bh * 2048 * 128;
  const short* vbase = vT + (long)bh * 128 * 2048;

  // stage split across 2 waves: wave w loads K rows w*32..w*32+31 (4 rows/instr, 8 instrs)
  // and V rows w*64..w*64+63 (8 rows/instr, 8 instrs). Swizzle identities preserved:
  // (w*32+p*4+kq)&15 == (p*4+kq)&15 and (w*64+p*8+vrow8)&7 == vrow8&7.
#define STAGE(JT) {                                                                   \
    for (int p = 0; p < 8; ++p) {                                                     \
      int r = w * 32 + p * 4 + kq;                                                    \
      int kch = l16 ^ ((p * 4 + kq) & 15);                                            \
      gload16(&kbase[((long)((JT) * 64 + r)) * 128 + kch * 8], &ks[(w * 32 + p * 4) * 128]); \
      int r2 = w * 64 + p * 8 + vrow8;                                                \
      gload16(&vbase[(long)r2 * 2048 + (JT) * 64 + vchunk * 8], &vs[(w * 64 + p * 8) * 64]); \
    }                                                                                 \
  }

  for (int jt = 0; jt <= qt; ++jt) {
    if (jt) __syncthreads();          // both waves done reading previous tile
    STAGE(jt)
    __syncthreads();                  // stage landed (vmcnt drain folded in)

    // S^T = K·Q^T  (wave: 64 keys x 32 q)
    f32x4 s[2][4] = {};
#pragma unroll
    for (int nt = 0; nt < 4; ++nt)
#pragma unroll
      for (int kk = 0; kk < 4; ++kk) {
        bf16x8 bk = *(const bf16x8*)&ks[(nt * 16 + l16) * 128 + (((kk * 4 + quad) ^ l16) * 8)];
        s[0][nt] = __builtin_amdgcn_mfma_f32_16x16x32_bf16(bk, aq[0][kk], s[0][nt], 0, 0, 0);
        s[1][nt] = __builtin_amdgcn_mfma_f32_16x16x32_bf16(bk, aq[1][kk], s[1][nt], 0, 0, 0);
      }
    if (jt == qt) {   // diagonal tile: causal mask
#pragma unroll
      for (int mt = 0; mt < 2; ++mt)
#pragma unroll
        for (int nt = 0; nt < 4; ++nt) {
          int q = qt * 64 + w * 32 + mt * 16 + l16;
#pragma unroll
          for (int r = 0; r < 4; ++r) {
            int key = jt * 64 + nt * 16 + quad * 4 + r;
            if (key > q) s[mt][nt][r] = -3.0e38f;
          }
        }
    }
    bf16x4 pb[2][4];
#pragma unroll
    for (int mt = 0; mt < 2; ++mt) {
      // per-q max: in-register tree + 2 cross-lane xors (q = l16; quads hold different keys)
      f32x4 vm;
#pragma unroll
      for (int r = 0; r < 4; ++r)
        vm[r] = fmaxf(fmaxf(s[mt][0][r], s[mt][1][r]), fmaxf(s[mt][2][r], s[mt][3][r]));
      float mx = fmaxf(fmaxf(vm[0], vm[1]), fmaxf(vm[2], vm[3]));
      mx = fmaxf(mx, __shfl_xor(mx, 16));
      mx = fmaxf(mx, __shfl_xor(mx, 32));
      // defer-max (T13): only rescale when the tile max grew past THR=8 (log2 units; P <= 2^8)
      if (!__all(mx <= mst[mt] + 8.0f)) {
        float nm = fmaxf(mst[mt], mx);
        float al = __builtin_amdgcn_exp2f(mst[mt] - nm);
        mst[mt] = nm;
        Lacc[mt] *= al;
#pragma unroll
        for (int dt = 0; dt < 8; ++dt) O[mt][dt] *= al;
      }
      // P = exp2(S^T - m) -> bf16 B-fragments (truncating cvt), directly in registers
#pragma unroll
      for (int nt = 0; nt < 4; ++nt) {
        bf16x4 p;
#pragma unroll
        for (int r = 0; r < 4; ++r) p[r] = f2bf_t(__builtin_amdgcn_exp2f(s[mt][nt][r] - mst[mt]));
        pb[mt][nt] = p;
      }
    }
    // O^T += V^T·P^T ; Lacc += 1·P^T   (16x16x16, k=16 keys per step)
#pragma unroll
    for (int nt = 0; nt < 4; ++nt) {
      int coff = ((nt * 2 + (quad >> 1)) ^ (l16 & 7)) * 8 + (quad & 1) * 4;
      bf16x4 av[8];
#pragma unroll
      for (int dt = 0; dt < 8; ++dt) av[dt] = *(const bf16x4*)&vs[(dt * 16 + l16) * 64 + coff];
#pragma unroll
      for (int mt = 0; mt < 2; ++mt) {
#pragma unroll
        for (int dt = 0; dt < 8; ++dt)
          O[mt][dt] = __builtin_amdgcn_mfma_f32_16x16x16bf16_1k(av[dt], pb[mt][nt], O[mt][dt], 0, 0, 0);
        Lacc[mt] = __builtin_amdgcn_mfma_f32_16x16x16bf16_1k(ones4, pb[mt][nt], Lacc[mt], 0, 0, 0);
      }
    }
  }
#undef STAGE
  // epilogue: y[q][h*128+d] = O^T[d][q] / l[q]; lane writes 4 consecutive d per (mt,dt)
#pragma unroll
  for (int mt = 0; mt < 2; ++mt) {
    float inv = __builtin_amdgcn_rcpf(Lacc[mt][0]);
    int q = qt * 64 + w * 32 + mt * 16 + l16;
#pragma unroll
    for (int dt = 0; dt < 8; ++dt) {
      short4 s4;
      s4.x = f2bf(O[mt][dt][0] * inv);
      s4.y = f2bf(O[mt][dt][1] * inv);
      s4.z = f2bf(O[mt][dt][2] * inv);
      s4.w = f2bf(O[mt][dt][3] * inv);
      *(short4*)&y[((long)(b * 2048 + q)) * 2048 + h * 128 + dt * 16 + quad * 4] = s4;
    }
  }
}

extern "C" void kernel_launch(void* const* d_in, const int* in_sizes, int n_in,
                              void* d_out, int out_size, void* d_ws, size_t ws_size,
                              hipStream_t stream) {
  const float* x       = (const float*)d_in[0];
  const float* diag    = (const float*)d_in[1];
  const float* left_w  = (const float*)d_in[2];
  const float* right_w = (const float*)d_in[3];
  const float* right_b = (const float*)d_in[4];
  const float* bias_p  = (const float*)d_in[5];
  float* out = (float*)d_out;

  char* ws = (char*)d_ws;
  short* xb = (short*)(ws + 0);              // 33,554,432 B  (aliased as y after attention)
  short* LT = (short*)(ws + 33554432);       //  2,097,152 B
  short* WT = (short*)(ws + 35651584);       //  4,194,304 B
  short* xl = (short*)(ws + 39845888);       //  6,291,456 B
  short* yl = (short*)(ws + 46137344);       //  2,097,152 B
  short* qb = (short*)(ws + 48234496);       // 33,554,432 B
  short* kb = (short*)(ws + 81788928);       // 33,554,432 B
  short* vT = (short*)(ws + 115343360);      // 33,554,432 B
  short* y  = xb;

  cast_prep_kernel<<<28672, 256, 0, stream>>>(x, left_w, diag, right_w, xb, LT, WT);
  gemm_bt<<<dim3(256, 3), 256, 0, stream>>>(xb, LT, xl, 8192, 384, 2048);
  lori_gemm<<<dim3(64, 48), 256, 0, stream>>>(xb, xl, 384, WT, right_b, bias_p, 0, qb, kb, vT, nullptr);
  attn_kernel<<<dim3(2048), 128, 0, stream>>>(qb, kb, vT, y);
  gemm_bt<<<dim3(256, 1), 256, 0, stream>>>(y, LT + 3L * 128 * 2048, yl, 8192, 128, 2048);
  lori_gemm<<<dim3(64, 16), 256, 0, stream>>>(y, yl, 128, WT, right_b, bias_p, 3, nullptr, nullptr, nullptr, out);
}